// Round 11
// baseline (687.650 us; speedup 1.0000x reference)
//
#include <hip/hip_runtime.h>
#include <hip/hip_bf16.h>

#define IN_DIM  512
#define HID     1024
#define OUT_DIM 512
#define BATCH   4096
#define T_STEPS 32

typedef __attribute__((ext_vector_type(8))) short bf16x8;
typedef __attribute__((ext_vector_type(4))) float f32x4;

__device__ inline void gload16(const void* g, void* l) {
  __builtin_amdgcn_global_load_lds(
      (const __attribute__((address_space(1))) void*)g,
      (__attribute__((address_space(3))) void*)l, 16, 0, 0);
}

// D[b][i] = sum_k A[b][k] * B[i][k], then relu(D + bias[i]).
// R11: tile 128(b) x 128(i), BK=64, 4 waves (2x2) each 64x64 (acc[4][4]).
// vs R7 (4 waves of 64x32 on 128x64): LDS bytes/FLOP -33%, barriers/FLOP
// -50%, 32 MFMA per wave-iter. Grid 256 = 1 block/CU (trade vs R7's 2).
// T4 counted vmcnt depth-2 (vmcnt(8), never 0 in loop) + raw s_barrier pair;
// T2 both-sides XOR swizzle; T5 setprio; XCD-stable batch panels; nt-store Cf.
// A: [4096][K] bf16 row-major; B: [Ntot][K] bf16 row-major (k-contiguous)
// Cf: f32 transposed Cf[i*BATCH+b]; Cb: bf16 Cb[b*Nld+i] (may be null)
__global__ __launch_bounds__(256, 2) void gemm_bt_bias_relu(
    const __hip_bfloat16* __restrict__ A,
    const __hip_bfloat16* __restrict__ B,
    const float* __restrict__ bias,
    float* __restrict__ Cf,
    __hip_bfloat16* __restrict__ Cb,
    int K, int Nld, int nx)
{
  // bijective XCD swizzle (nwg % 8 == 0: 256 or 128)
  const int nwg = gridDim.x;
  const int q   = nwg >> 3;
  const int bid = blockIdx.x;
  const int swz = (bid & 7) * q + (bid >> 3);
  const int bxi = swz % nx;          // neuron-tile index
  const int byi = swz / nx;          // batch-panel index (stable per XCD)
  const int brow = byi * 128;
  const int bcol = bxi * 128;

  const int tid  = threadIdx.x;
  const int lane = tid & 63;
  const int wid  = tid >> 6;
  const int wr   = wid >> 1, wc = wid & 1;   // 2x2 waves: wave tile 64(b) x 64(i)
  const int l15  = lane & 15, l4 = lane >> 4;
  const int srow = lane >> 3;
  const int schunk = (lane & 7) ^ (srow & 7);   // T2 stage-side pre-swizzle

  __shared__ __hip_bfloat16 Alds[2][128 * 64];  // 2 x 16 KB
  __shared__ __hip_bfloat16 Blds[2][128 * 64];  // 2 x 16 KB (64 KB total)

  f32x4 acc[4][4] = {};
  const int nt = K >> 6;   // 8 or 16, always >= 2

  // 8 gload16 per wave per tile (4 A rounds + 4 B rounds, 128 rows each)
  auto stage = [&](int ti, int buf) {
    const int kt = ti << 6;
#pragma unroll
    for (int it = 0; it < 4; ++it) {
      const int rowbase = it * 32 + wid * 8;           // wave-uniform LDS base
      gload16(A + (size_t)(brow + rowbase + srow) * K + kt + schunk * 8,
              &Alds[buf][rowbase * 64]);
    }
#pragma unroll
    for (int it = 0; it < 4; ++it) {
      const int rowbase = it * 32 + wid * 8;
      gload16(B + (size_t)(bcol + rowbase + srow) * K + kt + schunk * 8,
              &Blds[buf][rowbase * 64]);
    }
  };

  // ---- prologue: two tiles in flight ----
  stage(0, 0);
  stage(1, 1);

  const int rxor = l15 & 7;   // (row & 7) for all fragment rows this lane reads

  for (int ti = 0; ti < nt; ++ti) {
    const int buf = ti & 1;
    // T4: wait current tile's 8 loads; keep next tile's 8 in flight
    if (ti < nt - 1) {
      asm volatile("s_waitcnt vmcnt(8)" ::: "memory");
    } else {
      asm volatile("s_waitcnt vmcnt(0)" ::: "memory");
    }
    __builtin_amdgcn_s_barrier();
    __builtin_amdgcn_sched_barrier(0);   // rule 18: pin ds_reads below the wait

    __builtin_amdgcn_s_setprio(1);
#pragma unroll
    for (int ks = 0; ks < 2; ++ks) {
      bf16x8 af[4], bfr[4];
      const int cp = ((ks * 4 + l4) ^ rxor) * 8;   // T2 read-side XOR (16B chunks)
#pragma unroll
      for (int m = 0; m < 4; ++m)
        af[m] = *(const bf16x8*)&Alds[buf][(wr * 64 + m * 16 + l15) * 64 + cp];
#pragma unroll
      for (int n = 0; n < 4; ++n)
        bfr[n] = *(const bf16x8*)&Blds[buf][(wc * 64 + n * 16 + l15) * 64 + cp];
#pragma unroll
      for (int m = 0; m < 4; ++m)
#pragma unroll
        for (int n = 0; n < 4; ++n)
          acc[m][n] = __builtin_amdgcn_mfma_f32_16x16x32_bf16(af[m], bfr[n], acc[m][n], 0, 0, 0);
    }
    __builtin_amdgcn_s_setprio(0);

    asm volatile("s_waitcnt lgkmcnt(0)" ::: "memory");  // all reads of buf done
    __builtin_amdgcn_sched_barrier(0);
    __builtin_amdgcn_s_barrier();
    __builtin_amdgcn_sched_barrier(0);                  // pin stage below barrier
    if (ti < nt - 2) stage(ti + 2, buf);                // refill consumed buffer
  }

  // ---- epilogue: bias + relu, dual store (R7 form; Cb scatter is
  // L2-absorbed — R10 measured the LDS bounce as neutral) ----
#pragma unroll
  for (int n = 0; n < 4; ++n) {
    const int i = bcol + wc * 64 + n * 16 + l15;
    const float bv = bias[i];
#pragma unroll
    for (int m = 0; m < 4; ++m) {
      const int b0 = brow + wr * 64 + m * 16 + l4 * 4;
      f32x4 v = acc[m][n];
      f32x4 o;
      o[0] = fmaxf(v[0] + bv, 0.0f);
      o[1] = fmaxf(v[1] + bv, 0.0f);
      o[2] = fmaxf(v[2] + bv, 0.0f);
      o[3] = fmaxf(v[3] + bv, 0.0f);
      __builtin_nontemporal_store(o, (f32x4*)(Cf + (size_t)i * BATCH + b0));
      if (Cb) {
        Cb[(size_t)(b0 + 0) * Nld + i] = __float2bfloat16(o[0]);
        Cb[(size_t)(b0 + 1) * Nld + i] = __float2bfloat16(o[1]);
        Cb[(size_t)(b0 + 2) * Nld + i] = __float2bfloat16(o[2]);
        Cb[(size_t)(b0 + 3) * Nld + i] = __float2bfloat16(o[3]);
      }
    }
  }
}

// fused f32 -> bf16 convert for the 3 weight matrices (dst contiguous in ws)
__global__ __launch_bounds__(256) void convert_weights(
    const float* __restrict__ w_in, const float* __restrict__ w_rec,
    const float* __restrict__ w_out, __hip_bfloat16* __restrict__ dst)
{
  const int i = blockIdx.x * blockDim.x + threadIdx.x;   // float4 index
  const int n1 = (HID * IN_DIM) / 4;
  const int n2 = n1 + (HID * HID) / 4;
  const int nT = n2 + (OUT_DIM * HID) / 4;
  if (i >= nT) return;
  const float* src;
  int local;
  if (i < n1)       { src = w_in;  local = i; }
  else if (i < n2)  { src = w_rec; local = i - n1; }
  else              { src = w_out; local = i - n2; }
  float4 v = ((const float4*)src)[local];
  union { __hip_bfloat16 h[4]; ushort4 u; } p;
  p.h[0] = __float2bfloat16(v.x);
  p.h[1] = __float2bfloat16(v.y);
  p.h[2] = __float2bfloat16(v.z);
  p.h[3] = __float2bfloat16(v.w);
  ((ushort4*)dst)[i] = p.u;
}

// in[R][C] f32 -> out[C][R] bf16 (LDS 32x32 tile transpose)
__global__ __launch_bounds__(256) void transpose_f32_bf16(
    const float* __restrict__ in, __hip_bfloat16* __restrict__ out, int R, int C)
{
  __shared__ float tile[32][33];
  const int c0 = blockIdx.x * 32, r0 = blockIdx.y * 32;
  const int tx = threadIdx.x & 31, ty = threadIdx.x >> 5;
#pragma unroll
  for (int dy = 0; dy < 32; dy += 8)
    tile[ty + dy][tx] = in[(size_t)(r0 + ty + dy) * C + c0 + tx];
  __syncthreads();
#pragma unroll
  for (int dy = 0; dy < 32; dy += 8)
    out[(size_t)(c0 + ty + dy) * R + r0 + tx] = __float2bfloat16(tile[tx][ty + dy]);
}

extern "C" void kernel_launch(void* const* d_in, const int* in_sizes, int n_in,
                              void* d_out, int out_size, void* d_ws, size_t ws_size,
                              hipStream_t stream)
{
  const float* x     = (const float*)d_in[0];   // [512][4096]
  const float* W_in  = (const float*)d_in[1];   // [1024][512]
  const float* b_in  = (const float*)d_in[2];   // [1024]
  const float* W_rec = (const float*)d_in[3];   // [1024][1024]
  const float* b_rec = (const float*)d_in[4];   // [1024]
  const float* W_out = (const float*)d_in[5];   // [512][1024]
  const float* b_out = (const float*)d_in[6];   // [512]

  float* out0 = (float*)d_out;                        // [512][4096]
  float* itm  = out0 + (size_t)OUT_DIM * BATCH;       // [33][1024][4096]

  __hip_bfloat16* xT = (__hip_bfloat16*)d_ws;         // [4096][512]
  __hip_bfloat16* Wi = xT + (size_t)BATCH * IN_DIM;   // [1024][512]
  __hip_bfloat16* Wr = Wi + (size_t)HID * IN_DIM;     // [1024][1024]
  __hip_bfloat16* Wo = Wr + (size_t)HID * HID;        // [512][1024]
  __hip_bfloat16* h0 = Wo + (size_t)OUT_DIM * HID;    // [4096][1024]
  __hip_bfloat16* h1 = h0 + (size_t)BATCH * HID;      // [4096][1024]

  // input conversions: transpose x, convert all 3 weights in one launch
  transpose_f32_bf16<<<dim3(BATCH / 32, IN_DIM / 32), 256, 0, stream>>>(x, xT, IN_DIM, BATCH);
  {
    const int nT = (HID * IN_DIM + HID * HID + OUT_DIM * HID) / 4;
    convert_weights<<<(nT + 255) / 256, 256, 0, stream>>>(W_in, W_rec, W_out, Wi);
  }

  // y0 = relu(W_in @ x + b_in): grid 256, nx = 8, K = 512
  gemm_bt_bias_relu<<<(HID / 128) * (BATCH / 128), 256, 0, stream>>>(
      xT, Wi, b_in, itm, h0, IN_DIM, HID, HID / 128);

  // 32 recurrent steps: grid 256, nx = 8, K = 1024
  __hip_bfloat16* cur = h0;
  __hip_bfloat16* nxt = h1;
  for (int t = 0; t < T_STEPS; ++t) {
    float* dst = itm + (size_t)(t + 1) * HID * BATCH;
    gemm_bt_bias_relu<<<(HID / 128) * (BATCH / 128), 256, 0, stream>>>(
        cur, Wr, b_rec, dst, nxt, HID, HID, HID / 128);
    __hip_bfloat16* tmp = cur; cur = nxt; nxt = tmp;
  }

  // out = relu(W_out @ h_last + b_out): grid 128, nx = 4
  gemm_bt_bias_relu<<<(OUT_DIM / 128) * (BATCH / 128), 256, 0, stream>>>(
      cur, Wo, b_out, out0, (__hip_bfloat16*)nullptr, HID, 0, OUT_DIM / 128);
}

// Round 12
// 503.554 us; speedup vs baseline: 1.3656x; 1.3656x over previous
//
#include <hip/hip_runtime.h>
#include <hip/hip_bf16.h>

#define IN_DIM  512
#define HID     1024
#define OUT_DIM 512
#define BATCH   4096
#define T_STEPS 32

typedef __attribute__((ext_vector_type(8))) short bf16x8;
typedef __attribute__((ext_vector_type(4))) float f32x4;

__device__ inline void gload16(const void* g, void* l) {
  __builtin_amdgcn_global_load_lds(
      (const __attribute__((address_space(1))) void*)g,
      (__attribute__((address_space(3))) void*)l, 16, 0, 0);
}

// 16B B-fragment load straight to VGPRs. asm so OUR counted vmcnt governs it
// (compiler treats the def as synchronous; the explicit vmcnt ledger is the
// only guard — R8-validated semantics). "memory" pins issue order.
__device__ inline void bload(bf16x8 &d, const __hip_bfloat16* p) {
  asm volatile("global_load_dwordx4 %0, %1, off"
               : "=&v"(d) : "v"(p) : "memory");
}

// D[b][i] = sum_k A[b][k] * Wt[i][k], then relu(D + bias[i]).
// R12: B (weights) NEVER touches LDS. Weights are pre-tiled in MFMA-fragment
// order (16-col i-tile x 32-k slice = 512 elems in lane order), so a wave's
// B-frag is one coalesced global_load_dwordx4 at base + lane*16 from the
// XCD-local L2. LDS now holds only A (dbuf 32 KB): -33% LDS traffic vs R7.
// Rest is R7-verbatim: tile 128(b) x 64(i), BK=64, 4 waves (2x2), 2 blocks/CU,
// counted vmcnt (8 ops/tile: 4 A-gloads + 4 B-loads, never 0 in loop),
// T2 both-sides XOR swizzle on A, T5 setprio, XCD-stable batch panels,
// nt-store Cf, scatter Cb (R10: LDS bounce neutral).
// A:  [4096][K] bf16 row-major
// Wt: fragment-tiled weights, elem W[i][k] at
//     ((i>>4)*(K>>5) + (k>>5))*512 + ((k>>3)&3)*128 + (i&15)*8 + (k&7)
// Cf: f32 transposed Cf[i*BATCH+b]; Cb: bf16 Cb[b*Nld+i] (may be null)
__global__ __launch_bounds__(256, 2) void gemm_bt_bias_relu(
    const __hip_bfloat16* __restrict__ A,
    const __hip_bfloat16* __restrict__ Wt,
    const float* __restrict__ bias,
    float* __restrict__ Cf,
    __hip_bfloat16* __restrict__ Cb,
    int K, int Nld, int nx)
{
  // bijective XCD swizzle (nwg % 8 == 0: 512 or 256)
  const int nwg = gridDim.x;
  const int q   = nwg >> 3;
  const int bid = blockIdx.x;
  const int swz = (bid & 7) * q + (bid >> 3);
  const int bxi = swz % nx;          // neuron-tile index
  const int byi = swz / nx;          // batch-panel index (stable per XCD)
  const int brow = byi * 128;
  const int bcol = bxi * 64;

  const int tid  = threadIdx.x;
  const int lane = tid & 63;
  const int wid  = tid >> 6;
  const int wr   = wid >> 1, wc = wid & 1;   // 2x2 waves: wave tile 64(b) x 32(i)
  const int l15  = lane & 15, l4 = lane >> 4;
  const int srow = lane >> 3;
  const int schunk = (lane & 7) ^ (srow & 7);   // T2 stage-side pre-swizzle (A)

  __shared__ __hip_bfloat16 Alds[2][128 * 64];  // 2 x 16 KB (total 32 KB)

  f32x4 acc[4][2] = {};
  const int nt = K >> 6;   // 8 or 16 (even, >= 2)

  // A staging: 4 gload16 per wave per tile
  auto stageA = [&](int ti, int buf) {
    const int kt = ti << 6;
#pragma unroll
    for (int it = 0; it < 4; ++it) {
      const int rowbase = it * 32 + wid * 8;           // wave-uniform LDS base
      gload16(A + (size_t)(brow + rowbase + srow) * K + kt + schunk * 8,
              &Alds[buf][rowbase * 64]);
    }
  };

  // tiled-W fragment pointers: frag(n, slice s) = wt[n] + s*512 + lane*8
  const int Ks = K >> 5;   // 32-k slices
  const __hip_bfloat16* wt[2];
  wt[0] = Wt + (size_t)((bcol >> 4) + wc * 2 + 0) * Ks * 512 + lane * 8;
  wt[1] = Wt + (size_t)((bcol >> 4) + wc * 2 + 1) * Ks * 512 + lane * 8;

  // two named register banks for B (rule 20: no runtime indexing)
  bf16x8 bx[2][2], by[2][2];   // [n][ks]

  // ---- prologue: B(0)->bx | A(0) | B(1)->by | A(1)  (ledger order) ----
#pragma unroll
  for (int n = 0; n < 2; ++n) {
    bload(bx[n][0], wt[n] + 0 * 512);
    bload(bx[n][1], wt[n] + 1 * 512);
  }
  __builtin_amdgcn_sched_barrier(0);
  stageA(0, 0);
  __builtin_amdgcn_sched_barrier(0);
#pragma unroll
  for (int n = 0; n < 2; ++n) {
    bload(by[n][0], wt[n] + 2 * 512);
    bload(by[n][1], wt[n] + 3 * 512);
  }
  __builtin_amdgcn_sched_barrier(0);
  stageA(1, 1);

  const int rxor = l15 & 7;

  // one pipeline iteration; cb = B bank for tile ti (reloaded for ti+2)
  auto iterf = [&](int ti, bf16x8 (&cb)[2][2]) {
    const int buf = ti & 1;
    // steady ledger at top: [B(ti),A(ti),B(ti+1),A(ti+1)] outstanding (16);
    // vmcnt(8) -> B(ti)+A(ti) complete, next tile's 8 stay in flight.
    if (ti < nt - 1) {
      asm volatile("s_waitcnt vmcnt(8)" ::: "memory");
    } else {
      asm volatile("s_waitcnt vmcnt(0)" ::: "memory");
    }
    __builtin_amdgcn_s_barrier();
    __builtin_amdgcn_sched_barrier(0);   // rule 18: pin ds_reads below the wait

    __builtin_amdgcn_s_setprio(1);
#pragma unroll
    for (int ks = 0; ks < 2; ++ks) {
      bf16x8 af[4];
      const int cp = ((ks * 4 + l4) ^ rxor) * 8;   // T2 read-side XOR (A)
#pragma unroll
      for (int m = 0; m < 4; ++m)
        af[m] = *(const bf16x8*)&Alds[buf][(wr * 64 + m * 16 + l15) * 64 + cp];
#pragma unroll
      for (int m = 0; m < 4; ++m)
#pragma unroll
        for (int n = 0; n < 2; ++n)
          acc[m][n] = __builtin_amdgcn_mfma_f32_16x16x32_bf16(af[m], cb[n][ks], acc[m][n], 0, 0, 0);
    }
    __builtin_amdgcn_s_setprio(0);
    __builtin_amdgcn_sched_barrier(0);   // keep bloads below the MFMAs (WAR)

    if (ti + 2 < nt) {                   // refill this bank for tile ti+2
      const int s0 = (ti + 2) * 2;
#pragma unroll
      for (int n = 0; n < 2; ++n) {
        bload(cb[n][0], wt[n] + (s0 + 0) * 512);
        bload(cb[n][1], wt[n] + (s0 + 1) * 512);
      }
    }

    asm volatile("s_waitcnt lgkmcnt(0)" ::: "memory");  // A reads of buf done
    __builtin_amdgcn_sched_barrier(0);
    __builtin_amdgcn_s_barrier();
    __builtin_amdgcn_sched_barrier(0);
    if (ti + 2 < nt) stageA(ti + 2, buf);               // refill consumed A buf
  };

  for (int ti = 0; ti < nt; ti += 2) {
    iterf(ti,     bx);
    iterf(ti + 1, by);
  }

  // ---- epilogue: bias + relu, dual store ----
#pragma unroll
  for (int n = 0; n < 2; ++n) {
    const int i = bcol + wc * 32 + n * 16 + l15;
    const float bv = bias[i];
#pragma unroll
    for (int m = 0; m < 4; ++m) {
      const int b0 = brow + wr * 64 + m * 16 + l4 * 4;
      f32x4 v = acc[m][n];
      f32x4 o;
      o[0] = fmaxf(v[0] + bv, 0.0f);
      o[1] = fmaxf(v[1] + bv, 0.0f);
      o[2] = fmaxf(v[2] + bv, 0.0f);
      o[3] = fmaxf(v[3] + bv, 0.0f);
      __builtin_nontemporal_store(o, (f32x4*)(Cf + (size_t)i * BATCH + b0));
      if (Cb) {
        Cb[(size_t)(b0 + 0) * Nld + i] = __float2bfloat16(o[0]);
        Cb[(size_t)(b0 + 1) * Nld + i] = __float2bfloat16(o[1]);
        Cb[(size_t)(b0 + 2) * Nld + i] = __float2bfloat16(o[2]);
        Cb[(size_t)(b0 + 3) * Nld + i] = __float2bfloat16(o[3]);
      }
    }
  }
}

// f32 -> bf16 convert of the 3 weight matrices into FRAGMENT-TILED layout.
// One thread per 8-elem k-chunk: W[i][k0..k0+7] -> tiled offset.
__global__ __launch_bounds__(256) void convert_weights_tiled(
    const float* __restrict__ w_in, const float* __restrict__ w_rec,
    const float* __restrict__ w_out,
    __hip_bfloat16* __restrict__ wi, __hip_bfloat16* __restrict__ wr,
    __hip_bfloat16* __restrict__ wo)
{
  const int c  = blockIdx.x * blockDim.x + threadIdx.x;
  const int c1 = HID * IN_DIM / 8;          // 65536
  const int c2 = c1 + HID * HID / 8;        // 196608
  const int c3 = c2 + OUT_DIM * HID / 8;    // 262144
  const float* src; __hip_bfloat16* dst; int K, local;
  if (c < c1)      { src = w_in;  dst = wi; K = IN_DIM; local = c; }
  else if (c < c2) { src = w_rec; dst = wr; K = HID;    local = c - c1; }
  else if (c < c3) { src = w_out; dst = wo; K = HID;    local = c - c2; }
  else return;
  const int kc8 = K >> 3;
  const int i  = local / kc8;
  const int k0 = (local - i * kc8) << 3;
  const float4 a = *(const float4*)(src + (size_t)i * K + k0);
  const float4 b = *(const float4*)(src + (size_t)i * K + k0 + 4);
  union { __hip_bfloat16 h[8]; bf16x8 v; } p;
  p.h[0] = __float2bfloat16(a.x); p.h[1] = __float2bfloat16(a.y);
  p.h[2] = __float2bfloat16(a.z); p.h[3] = __float2bfloat16(a.w);
  p.h[4] = __float2bfloat16(b.x); p.h[5] = __float2bfloat16(b.y);
  p.h[6] = __float2bfloat16(b.z); p.h[7] = __float2bfloat16(b.w);
  const size_t off = ((size_t)(i >> 4) * (K >> 5) + (k0 >> 5)) * 512
                   + ((k0 >> 3) & 3) * 128 + (i & 15) * 8;
  *(bf16x8*)(dst + off) = p.v;
}

// in[R][C] f32 -> out[C][R] bf16 (LDS 32x32 tile transpose)
__global__ __launch_bounds__(256) void transpose_f32_bf16(
    const float* __restrict__ in, __hip_bfloat16* __restrict__ out, int R, int C)
{
  __shared__ float tile[32][33];
  const int c0 = blockIdx.x * 32, r0 = blockIdx.y * 32;
  const int tx = threadIdx.x & 31, ty = threadIdx.x >> 5;
#pragma unroll
  for (int dy = 0; dy < 32; dy += 8)
    tile[ty + dy][tx] = in[(size_t)(r0 + ty + dy) * C + c0 + tx];
  __syncthreads();
#pragma unroll
  for (int dy = 0; dy < 32; dy += 8)
    out[(size_t)(c0 + ty + dy) * R + r0 + tx] = __float2bfloat16(tile[tx][ty + dy]);
}

extern "C" void kernel_launch(void* const* d_in, const int* in_sizes, int n_in,
                              void* d_out, int out_size, void* d_ws, size_t ws_size,
                              hipStream_t stream)
{
  const float* x     = (const float*)d_in[0];   // [512][4096]
  const float* W_in  = (const float*)d_in[1];   // [1024][512]
  const float* b_in  = (const float*)d_in[2];   // [1024]
  const float* W_rec = (const float*)d_in[3];   // [1024][1024]
  const float* b_rec = (const float*)d_in[4];   // [1024]
  const float* W_out = (const float*)d_in[5];   // [512][1024]
  const float* b_out = (const float*)d_in[6];   // [512]

  float* out0 = (float*)d_out;                        // [512][4096]
  float* itm  = out0 + (size_t)OUT_DIM * BATCH;       // [33][1024][4096]

  __hip_bfloat16* xT = (__hip_bfloat16*)d_ws;         // [4096][512]
  __hip_bfloat16* Wi = xT + (size_t)BATCH * IN_DIM;   // [1024][512] tiled
  __hip_bfloat16* Wr = Wi + (size_t)HID * IN_DIM;     // [1024][1024] tiled
  __hip_bfloat16* Wo = Wr + (size_t)HID * HID;        // [512][1024] tiled
  __hip_bfloat16* h0 = Wo + (size_t)OUT_DIM * HID;    // [4096][1024]
  __hip_bfloat16* h1 = h0 + (size_t)BATCH * HID;      // [4096][1024]

  // input conversions: transpose x; convert+tile all 3 weights in one launch
  transpose_f32_bf16<<<dim3(BATCH / 32, IN_DIM / 32), 256, 0, stream>>>(x, xT, IN_DIM, BATCH);
  {
    const int nC = (HID * IN_DIM + HID * HID + OUT_DIM * HID) / 8;  // 262144
    convert_weights_tiled<<<(nC + 255) / 256, 256, 0, stream>>>(
        W_in, W_rec, W_out, Wi, Wr, Wo);
  }

  // y0 = relu(W_in @ x + b_in): grid 512, nx = 16, K = 512
  gemm_bt_bias_relu<<<(HID / 64) * (BATCH / 128), 256, 0, stream>>>(
      xT, Wi, b_in, itm, h0, IN_DIM, HID, HID / 64);

  // 32 recurrent steps: grid 512, nx = 16, K = 1024
  __hip_bfloat16* cur = h0;
  __hip_bfloat16* nxt = h1;
  for (int t = 0; t < T_STEPS; ++t) {
    float* dst = itm + (size_t)(t + 1) * HID * BATCH;
    gemm_bt_bias_relu<<<(HID / 64) * (BATCH / 128), 256, 0, stream>>>(
        cur, Wr, b_rec, dst, nxt, HID, HID, HID / 64);
    __hip_bfloat16* tmp = cur; cur = nxt; nxt = tmp;
  }

  // out = relu(W_out @ h_last + b_out): grid 256, nx = 8, K = 1024
  gemm_bt_bias_relu<<<(OUT_DIM / 64) * (BATCH / 128), 256, 0, stream>>>(
      cur, Wo, b_out, out0, (__hip_bfloat16*)nullptr, HID, 0, OUT_DIM / 64);
}